// Round 1
// 127.406 us; speedup vs baseline: 1.0516x; 1.0516x over previous
//
#include <hip/hip_runtime.h>
#include <hip/hip_bf16.h>
#include <cfloat>
#include <math.h>

#define N_NODES 8192
#define M_EDGES 2048
#define D_IN    256
#define DH      8
#define NODE_CAP 32    // max edges per node; deg mean 8.2, std 2.9 -> 8.5 sigma margin
#define EDGE_CAP 128   // max nodes per edge; mean 32.8, std 5.7 -> 16 sigma margin
#define PROJ_BLOCKS ((N_NODES + M_EDGES) / 4)
#define ZERO_INTS (M_EDGES + 16)          // edge_cnt + emptyX + emptyE (contiguous)
#define ZERO_BLOCKS 9

__device__ __forceinline__ float wave_reduce_sum(float v) {
    #pragma unroll
    for (int m = 1; m < 64; m <<= 1) v += __shfl_xor(v, m, 64);
    return v;
}
__device__ __forceinline__ float wave_reduce_max(float v) {
    #pragma unroll
    for (int m = 1; m < 64; m <<= 1) v = fmaxf(v, __shfl_xor(v, m, 64));
    return v;
}
__device__ __forceinline__ float leaky(float t) { return t >= 0.f ? t : 0.2f * t; }
__device__ __forceinline__ float elu(float v) { return v > 0.f ? v : expm1f(v); }

// Kernel 1: WX = X@W (stored), WE = E@W (scores only), plus scalar scores.
// W is staged TRANSPOSED in LDS (Wt[d][c]) so each lane's 4 weights for dim d
// are one contiguous conflict-free ds_read_b128 (previous version: per-lane
// float4 global loads at stride 128 B = 64 distinct cache lines per load inst).
// Tail blocks zero edge_cnt/emptyX/emptyE (no separate memset dispatch).
__global__ __launch_bounds__(256) void proj_kernel(
    const float* __restrict__ X, const float* __restrict__ E,
    const float* __restrict__ W, const float* __restrict__ ax, const float* __restrict__ ae,
    float* __restrict__ WX,
    float* __restrict__ sx, float* __restrict__ se,
    float* __restrict__ s1, float* __restrict__ s2,
    int* __restrict__ zero_region) {
    if (blockIdx.x >= PROJ_BLOCKS) {
        int z = (blockIdx.x - PROJ_BLOCKS) * 256 + threadIdx.x;
        if (z < ZERO_INTS) zero_region[z] = 0;
        return;   // whole block returns before barrier: legal
    }
    __shared__ __align__(16) float Wt[DH][D_IN];   // 8 KB
    {
        int t = threadIdx.x;                       // row t of W
        float4 a = ((const float4*)W)[2 * t];      // W[t][0..3]
        float4 b = ((const float4*)W)[2 * t + 1];  // W[t][4..7]
        Wt[0][t] = a.x; Wt[1][t] = a.y; Wt[2][t] = a.z; Wt[3][t] = a.w;
        Wt[4][t] = b.x; Wt[5][t] = b.y; Wt[6][t] = b.z; Wt[7][t] = b.w;
    }
    __syncthreads();
    int wave = (blockIdx.x * blockDim.x + threadIdx.x) >> 6;
    int lane = threadIdx.x & 63;
    bool isX = wave < N_NODES;
    int row = isX ? wave : wave - N_NODES;
    const float* src = isX ? (X + (size_t)row * D_IN) : (E + (size_t)row * D_IN);
    float4 x4 = ((const float4*)src)[lane];        // X[row][4l..4l+3]
    float wxd[DH];
    #pragma unroll
    for (int d = 0; d < DH; d++) {
        float4 wv = *(const float4*)&Wt[d][4 * lane];  // W[4l..4l+3][d]
        float p = x4.x * wv.x + x4.y * wv.y + x4.z * wv.z + x4.w * wv.w;
        wxd[d] = wave_reduce_sum(p);
    }
    if (lane == 0) {
        if (isX) {
            float a0 = 0.f, a1 = 0.f;
            #pragma unroll
            for (int d = 0; d < DH; d++) {
                WX[row * DH + d] = wxd[d];
                a0 += wxd[d] * ax[d];        // sx
                a1 += wxd[d] * ae[DH + d];   // s2
            }
            sx[row] = a0; s2[row] = a1;
        } else {
            float a0 = 0.f, a1 = 0.f;
            #pragma unroll
            for (int d = 0; d < DH; d++) {
                a0 += wxd[d] * ax[DH + d];   // se
                a1 += wxd[d] * ae[d];        // s1
            }
            se[row] = a0; s1[row] = a1;
        }
    }
}

// Kernel 2: per-node scan of H row (LDS-atomic compaction — measured faster than
// ballot compaction, r5 post-mortem). Builds node->edge list, per-node softmax
// denom (no max-sub: |logit|<~30, f32-safe), transposed edge lists (counter
// atomics only), empty-node accumulation.
__global__ __launch_bounds__(256) void node_scan_kernel(
    const float* __restrict__ H, const float* __restrict__ WX,
    const float* __restrict__ sx, const float* __restrict__ se,
    int* __restrict__ node_cnt, int* __restrict__ node_list,
    float* __restrict__ node_inv,
    int* __restrict__ edge_cnt, int* __restrict__ edge_list,
    float* __restrict__ emptyX) {
    __shared__ int s_cnt[4];
    __shared__ int s_list[4][NODE_CAP];
    int wv = threadIdx.x >> 6, lane = threadIdx.x & 63;
    int i = blockIdx.x * 4 + wv;
    if (lane == 0) s_cnt[wv] = 0;
    __syncthreads();
    const float4* Hrow = (const float4*)(H + (size_t)i * M_EDGES);
    float4 v[8];
    #pragma unroll
    for (int it = 0; it < 8; ++it) v[it] = Hrow[it * 64 + lane];   // all loads in flight
    #pragma unroll
    for (int it = 0; it < 8; ++it) {
        int c0 = (it * 64 + lane) * 4;
        if (v[it].x > 0.f) { int p = atomicAdd(&s_cnt[wv], 1); if (p < NODE_CAP) s_list[wv][p] = c0; }
        if (v[it].y > 0.f) { int p = atomicAdd(&s_cnt[wv], 1); if (p < NODE_CAP) s_list[wv][p] = c0 + 1; }
        if (v[it].z > 0.f) { int p = atomicAdd(&s_cnt[wv], 1); if (p < NODE_CAP) s_list[wv][p] = c0 + 2; }
        if (v[it].w > 0.f) { int p = atomicAdd(&s_cnt[wv], 1); if (p < NODE_CAP) s_list[wv][p] = c0 + 3; }
    }
    __syncthreads();
    int cnt = min(s_cnt[wv], NODE_CAP);
    if (cnt == 0) {
        // all-NEG_INF row -> uniform 1/M over every edge; accumulate WX[i]
        if (lane == 0) node_cnt[i] = 0;
        if (lane < DH) atomicAdd(&emptyX[lane], WX[i * DH + lane]);
        return;
    }
    float sxi = sx[i];
    int k = -1;
    float e = 0.f;
    if (lane < cnt) { k = s_list[wv][lane]; e = expf(leaky(sxi + se[k])); }
    float s = wave_reduce_sum(e);
    if (lane == 0) { node_cnt[i] = cnt; node_inv[i] = 1.f / s; }
    if (lane < cnt) {
        node_list[i * NODE_CAP + lane] = k;
        int p = atomicAdd(&edge_cnt[k], 1);
        if (p < EDGE_CAP) edge_list[k * EDGE_CAP + p] = i;
    }
}

// Kernel 3: per-edge gather. E_new[k] = elu(sum_i att[i,k]*WX[i] + emptyX/M).
// Also pass-2 softmax stats (m2_k, inv2_k) over the same member list.
__global__ __launch_bounds__(256) void edge_gather_kernel(
    const int* __restrict__ edge_cnt, const int* __restrict__ edge_list,
    const float* __restrict__ WX,
    const float* __restrict__ sx, const float* __restrict__ se,
    const float* __restrict__ s1, const float* __restrict__ s2,
    const float* __restrict__ node_inv,
    const float* __restrict__ emptyX,
    float* __restrict__ E_new, float* __restrict__ edge_m2, float* __restrict__ edge_inv2,
    float* __restrict__ emptyE) {
    int wv = threadIdx.x >> 6, lane = threadIdx.x & 63;
    int k = blockIdx.x * 4 + wv;
    int cnt = min(edge_cnt[k], EDGE_CAP);
    float sek = se[k], s1k = s1[k];
    float acc[DH];
    #pragma unroll
    for (int d = 0; d < DH; d++) acc[d] = 0.f;
    float lg2_0 = -FLT_MAX, lg2_1 = -FLT_MAX;
    bool h0 = lane < cnt, h1 = lane + 64 < cnt;
    if (h0) {
        int i0 = edge_list[k * EDGE_CAP + lane];
        float w = expf(leaky(sx[i0] + sek)) * node_inv[i0];
        const float4* wx4 = (const float4*)(WX + i0 * DH);
        float4 a = wx4[0], b = wx4[1];
        acc[0] += w * a.x; acc[1] += w * a.y; acc[2] += w * a.z; acc[3] += w * a.w;
        acc[4] += w * b.x; acc[5] += w * b.y; acc[6] += w * b.z; acc[7] += w * b.w;
        lg2_0 = leaky(s1k + s2[i0]);
    }
    if (h1) {
        int i1 = edge_list[k * EDGE_CAP + 64 + lane];
        float w = expf(leaky(sx[i1] + sek)) * node_inv[i1];
        const float4* wx4 = (const float4*)(WX + i1 * DH);
        float4 a = wx4[0], b = wx4[1];
        acc[0] += w * a.x; acc[1] += w * a.y; acc[2] += w * a.z; acc[3] += w * a.w;
        acc[4] += w * b.x; acc[5] += w * b.y; acc[6] += w * b.z; acc[7] += w * b.w;
        lg2_1 = leaky(s1k + s2[i1]);
    }
    #pragma unroll
    for (int d = 0; d < DH; d++) acc[d] = wave_reduce_sum(acc[d]);
    float m2 = wave_reduce_max(fmaxf(lg2_0, lg2_1));
    float e2 = (h0 ? expf(lg2_0 - m2) : 0.f) + (h1 ? expf(lg2_1 - m2) : 0.f);
    float sum2 = wave_reduce_sum(e2);
    if (lane == 0) {
        #pragma unroll
        for (int d = 0; d < DH; d++) {
            float en = elu(acc[d] + emptyX[d] * (1.0f / (float)M_EDGES));
            E_new[k * DH + d] = en;
            if (cnt == 0) atomicAdd(&emptyE[d], en);  // empty edge: uniform 1/N to all nodes
        }
        if (cnt > 0) { edge_m2[k] = m2; edge_inv2[k] = 1.f / sum2; }
    }
}

// Kernel 4: per-node gather; one WAVE per node. Lanes split as
// (edge-slot e0 = lane>>3, dim d = lane&7): 8 edges processed in parallel per
// iteration (mean deg 8.2 -> usually a single iteration of broadcast loads,
// vs the previous 8-deep serial dependent-load chain at 1 wave/SIMD).
__global__ __launch_bounds__(256) void node_gather_kernel(
    const int* __restrict__ node_cnt, const int* __restrict__ node_list,
    const float* __restrict__ s1, const float* __restrict__ s2,
    const float* __restrict__ edge_m2, const float* __restrict__ edge_inv2,
    const float* __restrict__ E_new, const float* __restrict__ emptyE,
    float* __restrict__ out) {
    int wv = threadIdx.x >> 6, lane = threadIdx.x & 63;
    int i = blockIdx.x * 4 + wv;
    int cnt = node_cnt[i];
    int e0 = lane >> 3;     // 0..7
    int d  = lane & 7;
    float s2i = s2[i];
    float acc = 0.f;
    for (int base = 0; base < cnt; base += 8) {
        int e = base + e0;
        if (e < cnt) {
            int k = node_list[i * NODE_CAP + e];       // broadcast across 8 d-lanes
            float w2 = expf(leaky(s1[k] + s2i) - edge_m2[k]) * edge_inv2[k];
            acc += w2 * E_new[k * DH + d];             // 32B contiguous per edge
        }
    }
    // sum across the 8 edge-slot groups (stride-8 lanes share d)
    acc += __shfl_xor(acc, 8, 64);
    acc += __shfl_xor(acc, 16, 64);
    acc += __shfl_xor(acc, 32, 64);
    if (lane < DH)
        out[i * DH + lane] = elu(acc + emptyE[lane] * (1.0f / (float)N_NODES));
}

extern "C" void kernel_launch(void* const* d_in, const int* in_sizes, int n_in,
                              void* d_out, int out_size, void* d_ws, size_t ws_size,
                              hipStream_t stream) {
    const float* X  = (const float*)d_in[0];
    const float* E  = (const float*)d_in[1];
    const float* H  = (const float*)d_in[2];
    const float* W  = (const float*)d_in[3];
    const float* ax = (const float*)d_in[4];
    const float* ae = (const float*)d_in[5];
    float* out = (float*)d_out;

    float* ws = (float*)d_ws;
    // workspace layout (float offsets)
    float* WX        = ws + 0;        // 65536
    float* sx        = ws + 65536;    // 8192
    float* se        = ws + 73728;    // 2048
    float* s1        = ws + 75776;    // 2048
    float* s2        = ws + 77824;    // 8192
    float* node_inv  = ws + 86016;    // 8192
    float* E_new     = ws + 94208;    // 16384
    float* edge_m2   = ws + 110592;   // 2048
    float* edge_inv2 = ws + 112640;   // 2048
    int*   node_cnt  = (int*)(ws + 114688);   // 8192
    int*   node_list = (int*)(ws + 122880);   // 8192*32 = 262144
    int*   edge_list = (int*)(ws + 385024);   // 2048*128 = 262144
    // ---- zero region (cleared by proj tail blocks) ----
    int*   edge_cnt  = (int*)(ws + 647168);   // 2048
    float* emptyX    = ws + 649216;   // 8
    float* emptyE    = ws + 649224;   // 8
    // total 649232 floats = 2.48 MB

    proj_kernel<<<PROJ_BLOCKS + ZERO_BLOCKS, 256, 0, stream>>>(
        X, E, W, ax, ae, WX, sx, se, s1, s2, edge_cnt);
    node_scan_kernel<<<N_NODES / 4, 256, 0, stream>>>(
        H, WX, sx, se, node_cnt, node_list, node_inv,
        edge_cnt, edge_list, emptyX);
    edge_gather_kernel<<<M_EDGES / 4, 256, 0, stream>>>(
        edge_cnt, edge_list, WX, sx, se, s1, s2, node_inv, emptyX,
        E_new, edge_m2, edge_inv2, emptyE);
    node_gather_kernel<<<N_NODES / 4, 256, 0, stream>>>(
        node_cnt, node_list, s1, s2, edge_m2, edge_inv2, E_new, emptyE, out);
}